// Round 3
// baseline (246.980 us; speedup 1.0000x reference)
//
#include <hip/hip_runtime.h>
#include <stdint.h>

#define TT 12
#define NN 325
#define HH 64
#define EE 32
#define LHH 128
#define OO 12
#define CIN 97
#define MOFF 65
#define BB 64

typedef __attribute__((ext_vector_type(8))) short bf8;
typedef __attribute__((ext_vector_type(4))) float f4;

__device__ __forceinline__ float sigf(float x) {
  return __builtin_amdgcn_rcpf(1.f + __builtin_amdgcn_exp2f(-1.4426950408889634f * x));
}
__device__ __forceinline__ float tanhfast(float x) {
  // tanh(x) = 1 - 2/(1+e^{2x});  e^{2x} = 2^{2x*log2e}
  return 1.f - 2.f * __builtin_amdgcn_rcpf(1.f + __builtin_amdgcn_exp2f(2.8853900817779268f * x));
}
__device__ __forceinline__ unsigned short f2bf(float f) {  // RNE float->bf16
  unsigned int u = __float_as_uint(f);
  u += 0x7fffu + ((u >> 16) & 1u);
  return (unsigned short)(u >> 16);
}
__device__ __forceinline__ float bf2f(unsigned short s) {
  return __uint_as_float(((unsigned int)s) << 16);
}

// ---------------------------------------------------------------------------
// k_prep (fused k_meta + k_wh): grid 264.
//  - Every block recomputes meta[64][32] (tiny, L2-hot).
//  - Blocks 0..255 (g = bi>>6, i = bi&63): recompute lwh hidden for gate g,
//    GEMM hid(64x128) @ W2-slice(128x64) -> bf16 Wh in MFMA B-frag order;
//    also the x-signal gather (spread across these 256 blocks).
//  - Blocks 256..263 (g = role>>1, isb = role&1): lwx / lb MLP -> wx_ws/bg_ws.
// ---------------------------------------------------------------------------
__global__ __launch_bounds__(256, 2) void k_prep(
    const float* __restrict__ x,
    const float* __restrict__ xw1, const float* __restrict__ xb1,
    const float* __restrict__ xw2, const float* __restrict__ xb2,
    const float* __restrict__ hw1, const float* __restrict__ hb1,
    const float* __restrict__ hw2, const float* __restrict__ hb2,
    const float* __restrict__ bw1, const float* __restrict__ bb1,
    const float* __restrict__ bw2, const float* __restrict__ bb2,
    unsigned short* __restrict__ whb, float* __restrict__ xg,
    float* __restrict__ wx_ws, float* __restrict__ bg_ws)
{
  const int bi = blockIdx.x, tid = threadIdx.x;
  __shared__ float meta_s[BB][EE];    // 8 KB
  __shared__ float hs[BB][132];       // hidden [b][l], padded
  __shared__ float w2s[LHH][HH];      // W2 slice [l][j]

  // meta for all 64 batches (every block; distinct bytes = 98 KB -> L2-hot)
  for (int m = tid; m < BB * EE; m += 256) {
    const int b = m >> 5, e = m & 31;
    float s = 0.f;
    #pragma unroll
    for (int t = 0; t < TT; ++t)
      s += x[(size_t)((b * TT + t) * NN) * CIN + MOFF + e];
    meta_s[b][e] = s * (1.f / 12.f);
  }

  if (bi < 256) {
    const int g = bi >> 6, i = bi & 63;

    // x-signal gather (parallel across the 256 GEMM blocks)
    const int base = bi * 976;
    #pragma unroll
    for (int kk = 0; kk < 4; ++kk) {
      const int flat = base + kk * 256 + tid;
      if (flat < BB * TT * NN) {
        const int b = flat / (TT * NN);
        const int r = flat - b * (TT * NN);
        const int t = r / NN;
        const int n = r - t * NN;
        xg[flat] = x[(size_t)((b * TT + t) * NN + n) * CIN];
      }
    }
    // W2 slice for cols i*64..i*64+63
    for (int idx = tid; idx < LHH * HH; idx += 256)
      w2s[idx >> 6][idx & 63] = hw2[(size_t)(g * LHH + (idx >> 6)) * 4096 + i * 64 + (idx & 63)];
    __syncthreads();  // meta_s ready

    // lwh hidden for gate g: hs[b][l] = relu(b1 + meta @ W1)
    for (int m = tid; m < BB * LHH; m += 256) {
      const int b = m >> 7, l = m & 127;
      float a = hb1[g * LHH + l];
      const float* w = hw1 + (size_t)g * (EE * LHH) + l;
      #pragma unroll
      for (int e = 0; e < EE; ++e) a = fmaf(meta_s[b][e], w[e * LHH], a);
      hs[b][l] = fmaxf(a, 0.f);
    }
    __syncthreads();

    // GEMM: 64x64 tile over K=128
    const int rg = tid >> 4, cg = tid & 15;
    const int b0 = rg * 4, j0 = cg * 4;
    float acc[4][4] = {};
    for (int l = 0; l < LHH; l += 4) {
      f4 hv[4];
      #pragma unroll
      for (int rr = 0; rr < 4; ++rr) hv[rr] = *(const f4*)&hs[b0 + rr][l];
      #pragma unroll
      for (int ll = 0; ll < 4; ++ll) {
        const f4 wv = *(const f4*)&w2s[l + ll][j0];
        #pragma unroll
        for (int rr = 0; rr < 4; ++rr)
          #pragma unroll
          for (int jj = 0; jj < 4; ++jj)
            acc[rr][jj] = fmaf(hv[rr][ll], wv[jj], acc[rr][jj]);
      }
    }
    // store bf16 in MFMA B-frag order
    const int kh = i >> 5, quad = (i >> 3) & 3, j8 = i & 7;
    #pragma unroll
    for (int rr = 0; rr < 4; ++rr) {
      const int b = b0 + rr;
      #pragma unroll
      for (int jj = 0; jj < 4; ++jj) {
        const int j = j0 + jj;
        const float v = acc[rr][jj] + hb2[g * 4096 + i * 64 + j];
        const int col = g * 64 + j;
        const int nt = col >> 4, c16 = col & 15;
        const int lane = quad * 16 + c16;
        whb[(size_t)((b * 32 + kh * 16 + nt) * 64 + lane) * 8 + j8] = f2bf(v);
      }
    }
  } else {
    const int role = bi - 256;       // 0..7
    const int g = role >> 1;
    const int isb = role & 1;        // 0 -> lwx (wx_ws), 1 -> lb (bg_ws)
    const float* W1 = isb ? bw1 : xw1;
    const float* B1 = isb ? bb1 : xb1;
    const float* W2 = isb ? bw2 : xw2;
    const float* B2 = isb ? bb2 : xb2;
    float* dst = isb ? bg_ws : wx_ws;
    __syncthreads();  // meta_s ready

    for (int m = tid; m < BB * LHH; m += 256) {
      const int b = m >> 7, l = m & 127;
      float a = B1[g * LHH + l];
      const float* w = W1 + (size_t)g * (EE * LHH) + l;
      #pragma unroll
      for (int e = 0; e < EE; ++e) a = fmaf(meta_s[b][e], w[e * LHH], a);
      hs[b][l] = fmaxf(a, 0.f);
    }
    __syncthreads();

    for (int m = tid; m < BB * HH; m += 256) {
      const int b = m >> 6, h = m & 63;
      float a = B2[g * HH + h];
      const float* w = W2 + (size_t)g * (LHH * HH) + h;
      #pragma unroll 8
      for (int l = 0; l < LHH; ++l) a = fmaf(hs[b][l], w[l * HH], a);
      dst[b * 256 + g * 64 + h] = a;
    }
  }
}

// ---------------------------------------------------------------------------
// k_lstm v3: grid (11 x-tiles of 32 rows, 64 batches), 256 thr = 4 waves.
// 704 blocks = 2.75 blocks/CU -> SINGLE co-residency pass at 3 blocks/CU
// (R2's 1344 blocks @4/CU ran a ~30%-occupancy second pass = the 38 us).
// Per step per wave: 2 independent row-tiles (2x ILP): 16 MFMAs, 80 trans.
// ---------------------------------------------------------------------------
__global__ __launch_bounds__(256, 3) void k_lstm(
    const float* __restrict__ xg, const float* __restrict__ wx_ws,
    const float* __restrict__ bg_ws, const unsigned short* __restrict__ whb,
    const float* __restrict__ fc1W, const float* __restrict__ fc1b,
    const float* __restrict__ fc2W, const float* __restrict__ fc2b,
    float* __restrict__ out)
{
  const int rb = blockIdx.x, b = blockIdx.y, tid = threadIdx.x;
  const int wave = tid >> 6, lane = tid & 63, quad = lane >> 4, c16 = lane & 15;
  const int n0 = rb * 32;

  __shared__ __align__(16) unsigned short Hs[2][2][16][72];  // [buf][tile][row][col], stride 144B
  __shared__ float Xs[TT][32];
  __shared__ float fc1s[HH * 32];
  __shared__ float fc2s[32 * OO];
  __shared__ float HIDs[32][36];
  __shared__ float fc1bs[32];
  __shared__ float fc2bs[OO];

  for (int idx = tid; idx < TT * 32; idx += 256) {
    const int t = idx >> 5, r = idx & 31, n = n0 + r;
    Xs[t][r] = (n < NN) ? xg[b * (TT * NN) + t * NN + n] : 0.f;
  }
  for (int idx = tid; idx < HH * 32; idx += 256) fc1s[idx] = fc1W[idx];
  for (int idx = tid; idx < 32 * OO; idx += 256) fc2s[idx] = fc2W[idx];
  if (tid < 32) fc1bs[tid] = fc1b[tid];
  if (tid < OO) fc2bs[tid] = fc2b[tid];

  // per-lane x-weight / bias for this wave's 4 gate-columns (col = g*64 + wave*16 + c16)
  float wxv[4], bgv[4];
  #pragma unroll
  for (int g = 0; g < 4; ++g) {
    wxv[g] = wx_ws[b * 256 + g * 64 + wave * 16 + c16];
    bgv[g] = bg_ws[b * 256 + g * 64 + wave * 16 + c16];
  }
  // resident Wh B-fragments for this wave's columns: nt = g*4 + wave
  bf8 wf[2][4];
  #pragma unroll
  for (int kh = 0; kh < 2; ++kh)
    #pragma unroll
    for (int g = 0; g < 4; ++g)
      wf[kh][g] = *(const bf8*)(whb + (size_t)((b * 32 + kh * 16 + g * 4 + wave) * 64 + lane) * 8);

  float cst[2][4];
  #pragma unroll
  for (int ta = 0; ta < 2; ++ta)
    #pragma unroll
    for (int r = 0; r < 4; ++r) cst[ta][r] = 0.f;

  __syncthreads();  // staging visible

  #pragma unroll 1
  for (int t = 0; t < TT; ++t) {
    bf8 af[2][2];
    if (t > 0) {
      #pragma unroll
      for (int ta = 0; ta < 2; ++ta) {
        af[ta][0] = *(const bf8*)&Hs[(t - 1) & 1][ta][c16][quad * 8];
        af[ta][1] = *(const bf8*)&Hs[(t - 1) & 1][ta][c16][32 + quad * 8];
      }
    }
    f4 ac[2][4];
    #pragma unroll
    for (int ta = 0; ta < 2; ++ta) {
      float xr[4];
      #pragma unroll
      for (int r = 0; r < 4; ++r) xr[r] = Xs[t][ta * 16 + quad * 4 + r];
      #pragma unroll
      for (int g = 0; g < 4; ++g)
        #pragma unroll
        for (int r = 0; r < 4; ++r)
          ac[ta][g][r] = fmaf(xr[r], wxv[g], bgv[g]);
    }
    if (t > 0) {
      #pragma unroll
      for (int ta = 0; ta < 2; ++ta)
        #pragma unroll
        for (int g = 0; g < 4; ++g) {
          ac[ta][g] = __builtin_amdgcn_mfma_f32_16x16x32_bf16(af[ta][0], wf[0][g], ac[ta][g], 0, 0, 0);
          ac[ta][g] = __builtin_amdgcn_mfma_f32_16x16x32_bf16(af[ta][1], wf[1][g], ac[ta][g], 0, 0, 0);
        }
    }
    #pragma unroll
    for (int ta = 0; ta < 2; ++ta)
      #pragma unroll
      for (int r = 0; r < 4; ++r) {
        const float gg = tanhfast(ac[ta][0][r]);
        const float ii = sigf(ac[ta][1][r]);
        const float ff = sigf(ac[ta][2][r]);
        const float oo = sigf(ac[ta][3][r]);
        const float cc = fmaf(gg, ii, cst[ta][r] * ff);
        cst[ta][r] = cc;
        const float hh = tanhfast(cc) * oo;
        Hs[t & 1][ta][quad * 4 + r][wave * 16 + c16] = f2bf(hh);
      }
    __syncthreads();
  }

  // ---- head, fp32. final h is in Hs[(TT-1)&1] == Hs[1]. ----
  // Step A: hid[32][32]: thread (row32 = tid&31, uu = tid>>5) does u = 4uu..4uu+3
  {
    const int row32 = tid & 31, uu = tid >> 5;
    const int ta = row32 >> 4, row = row32 & 15;
    float hacc[4];
    #pragma unroll
    for (int j = 0; j < 4; ++j) hacc[j] = fc1bs[uu * 4 + j];
    #pragma unroll
    for (int kc = 0; kc < 8; ++kc) {
      const bf8 hv = *(const bf8*)&Hs[1][ta][row][kc * 8];
      #pragma unroll
      for (int j8 = 0; j8 < 8; ++j8) {
        const float hk = fmaxf(bf2f((unsigned short)hv[j8]), 0.f);  // relu(h)
        const int k = kc * 8 + j8;
        #pragma unroll
        for (int j = 0; j < 4; ++j)
          hacc[j] = fmaf(hk, fc1s[k * 32 + uu * 4 + j], hacc[j]);
      }
    }
    #pragma unroll
    for (int j = 0; j < 4; ++j)
      HIDs[row32][uu * 4 + j] = fmaxf(hacc[j], 0.f);
  }
  __syncthreads();
  // Step B: out[row][o] = hid[row] @ fc2 + b2
  for (int idx = tid; idx < 32 * OO; idx += 256) {
    const int o = idx >> 5, row32 = idx & 31;
    float a = fc2bs[o];
    #pragma unroll
    for (int k = 0; k < 32; ++k)
      a = fmaf(HIDs[row32][k], fc2s[k * OO + o], a);
    const int n = n0 + row32;
    if (n < NN)
      out[b * (OO * NN) + o * NN + n] = a;
  }
}

// ---------------------------------------------------------------------------
extern "C" void kernel_launch(void* const* d_in, const int* in_sizes, int n_in,
                              void* d_out, int out_size, void* d_ws, size_t ws_size,
                              hipStream_t stream) {
  const float* x    = (const float*)d_in[0];
  const float* xw1  = (const float*)d_in[1];
  const float* xb1  = (const float*)d_in[2];
  const float* xw2  = (const float*)d_in[3];
  const float* xb2  = (const float*)d_in[4];
  const float* hw1  = (const float*)d_in[5];
  const float* hb1  = (const float*)d_in[6];
  const float* hw2  = (const float*)d_in[7];
  const float* hb2  = (const float*)d_in[8];
  const float* bw1  = (const float*)d_in[9];
  const float* bb1  = (const float*)d_in[10];
  const float* bw2  = (const float*)d_in[11];
  const float* bb2  = (const float*)d_in[12];
  const float* fc1W = (const float*)d_in[13];
  const float* fc1b = (const float*)d_in[14];
  const float* fc2W = (const float*)d_in[15];
  const float* fc2b = (const float*)d_in[16];
  float* out = (float*)d_out;

  float* ws = (float*)d_ws;
  float* wx_ws = ws;                         // [64][256]     = 16384 floats
  float* bg_ws = ws + 16384;                 // [64][256]     = 16384
  float* xg_ws = ws + 32768;                 // [64][12][325] = 249600
  unsigned short* whb = (unsigned short*)(ws + 32768 + BB * TT * NN);  // 1048576 u16

  k_prep<<<264, 256, 0, stream>>>(x, xw1, xb1, xw2, xb2, hw1, hb1, hw2, hb2,
                                  bw1, bb1, bw2, bb2, whb, xg_ws, wx_ws, bg_ws);
  k_lstm<<<dim3(11, 64), 256, 0, stream>>>(xg_ws, wx_ws, bg_ws, whb,
                                           fc1W, fc1b, fc2W, fc2b, out);
}

// Round 4
// 224.492 us; speedup vs baseline: 1.1002x; 1.1002x over previous
//
#include <hip/hip_runtime.h>
#include <stdint.h>

#define TT 12
#define NN 325
#define HH 64
#define EE 32
#define LHH 128
#define OO 12
#define CIN 97
#define MOFF 65
#define BB 64

typedef __attribute__((ext_vector_type(8))) short bf8;
typedef __attribute__((ext_vector_type(4))) float f4;

__device__ __forceinline__ float sigf(float x) {
  return __builtin_amdgcn_rcpf(1.f + __builtin_amdgcn_exp2f(-1.4426950408889634f * x));
}
__device__ __forceinline__ float tanhfast(float x) {
  // tanh(x) = 1 - 2/(1+e^{2x});  e^{2x} = 2^{2x*log2e}
  return 1.f - 2.f * __builtin_amdgcn_rcpf(1.f + __builtin_amdgcn_exp2f(2.8853900817779268f * x));
}
__device__ __forceinline__ unsigned short f2bf(float f) {  // RNE float->bf16
  unsigned int u = __float_as_uint(f);
  u += 0x7fffu + ((u >> 16) & 1u);
  return (unsigned short)(u >> 16);
}
__device__ __forceinline__ float bf2f(unsigned short s) {
  return __uint_as_float(((unsigned int)s) << 16);
}

// ---------------------------------------------------------------------------
// Kernel 1: meta = mean_t x[b,t,0,65:], 3 MLP hiddens, Wx / bias-gate outputs.
// grid 64 (one per batch), 256 threads. Meta gather is (t,e)-parallel
// (2 loads/thread max) instead of 32 threads x 12 serial strided loads.
// ---------------------------------------------------------------------------
__global__ __launch_bounds__(256) void k_meta(
    const float* __restrict__ x,
    const float* __restrict__ xw1, const float* __restrict__ xb1,
    const float* __restrict__ xw2, const float* __restrict__ xb2,
    const float* __restrict__ hw1, const float* __restrict__ hb1,
    const float* __restrict__ bw1, const float* __restrict__ bb1,
    const float* __restrict__ bw2, const float* __restrict__ bb2,
    float* __restrict__ hid_ws, float* __restrict__ wx_ws,
    float* __restrict__ bg_ws)
{
  const int b = blockIdx.x, tid = threadIdx.x;
  __shared__ float mpart[TT][EE];
  __shared__ float meta_s[EE];
  __shared__ float hidx_s[512], hidb_s[512];

  for (int idx = tid; idx < TT * EE; idx += 256) {
    const int t = idx >> 5, e = idx & 31;
    mpart[t][e] = x[(size_t)((b * TT + t) * NN) * CIN + MOFF + e];
  }
  __syncthreads();
  if (tid < EE) {
    float s = 0.f;
    #pragma unroll
    for (int t = 0; t < TT; ++t) s += mpart[t][tid];
    meta_s[tid] = s * (1.f / 12.f);
  }
  __syncthreads();

  // hiddens: 3 MLPs x 4 gates x 128
  for (int idx = tid; idx < 1536; idx += 256) {
    const int mlp = idx >> 9, rem = idx & 511;
    const int g = rem >> 7, l = rem & 127;
    const float* W1 = (mlp == 0) ? xw1 : ((mlp == 1) ? hw1 : bw1);
    const float* B1 = (mlp == 0) ? xb1 : ((mlp == 1) ? hb1 : bb1);
    float a = B1[rem];
    const float* w = W1 + g * (EE * LHH) + l;
    #pragma unroll
    for (int e = 0; e < EE; ++e) a = fmaf(meta_s[e], w[e * LHH], a);
    a = fmaxf(a, 0.f);
    if (mlp == 0) hidx_s[rem] = a;
    else if (mlp == 2) hidb_s[rem] = a;
    else hid_ws[g * (BB * LHH) + b * LHH + l] = a;  // lwh hidden -> ws for GEMM
  }
  __syncthreads();

  // Wx and gate-bias outputs (per (g,h)): 128-dot each
  {
    const int g = tid >> 6;
    const int h = tid & 63;
    float ax = xb2[tid];  // (4,64) flat == g*64+h == tid
    float ab = bb2[tid];
    const float* wxp = xw2 + (size_t)g * (LHH * HH) + h;
    const float* wbp = bw2 + (size_t)g * (LHH * HH) + h;
    const float* hx = hidx_s + g * LHH;
    const float* hb = hidb_s + g * LHH;
    #pragma unroll 8
    for (int l = 0; l < LHH; ++l) {
      ax = fmaf(hx[l], wxp[l * HH], ax);
      ab = fmaf(hb[l], wbp[l * HH], ab);
    }
    wx_ws[b * 256 + tid] = ax;
    bg_ws[b * 256 + tid] = ab;
  }
}

// ---------------------------------------------------------------------------
// Kernel 2: Wh GEMM per gate: hid(64b x 128) @ W2(128 x 4096) -> bf16 weights
// stored in exact MFMA B-fragment order; also gathers x signal into xg.
// grid 256: g = bi>>6, i (= contraction row of Wh, 0..63) = bi&63.
// ---------------------------------------------------------------------------
__global__ __launch_bounds__(256) void k_wh(
    const float* __restrict__ x,
    const float* __restrict__ hw2, const float* __restrict__ hb2,
    const float* __restrict__ hid_ws, unsigned short* __restrict__ whb,
    float* __restrict__ xg)
{
  const int g = blockIdx.x >> 6, i = blockIdx.x & 63, tid = threadIdx.x;
  __shared__ float hs[BB][132];       // hid[b][l], padded
  __shared__ float w2s[LHH][HH];      // W2 slice [l][j] for cols i*64..i*64+63

  // x-signal gather (parallel across the 256 blocks)
  {
    const int base = blockIdx.x * 976;
    #pragma unroll
    for (int kk = 0; kk < 4; ++kk) {
      const int flat = base + kk * 256 + tid;
      if (flat < BB * TT * NN) {
        const int b = flat / (TT * NN);
        const int r = flat - b * (TT * NN);
        const int t = r / NN;
        const int n = r - t * NN;
        xg[flat] = x[(size_t)((b * TT + t) * NN + n) * CIN];
      }
    }
  }

  for (int idx = tid; idx < BB * LHH; idx += 256)
    hs[idx >> 7][idx & 127] = hid_ws[g * (BB * LHH) + idx];
  for (int idx = tid; idx < LHH * HH; idx += 256)
    w2s[idx >> 6][idx & 63] = hw2[(size_t)(g * LHH + (idx >> 6)) * 4096 + i * 64 + (idx & 63)];
  __syncthreads();

  const int rg = tid >> 4, cg = tid & 15;
  const int b0 = rg * 4, j0 = cg * 4;
  float acc[4][4] = {};
  for (int l = 0; l < LHH; l += 4) {
    f4 hv[4];
    #pragma unroll
    for (int rr = 0; rr < 4; ++rr) hv[rr] = *(const f4*)&hs[b0 + rr][l];
    #pragma unroll
    for (int ll = 0; ll < 4; ++ll) {
      const f4 wv = *(const f4*)&w2s[l + ll][j0];
      #pragma unroll
      for (int rr = 0; rr < 4; ++rr)
        #pragma unroll
        for (int jj = 0; jj < 4; ++jj)
          acc[rr][jj] = fmaf(hv[rr][ll], wv[jj], acc[rr][jj]);
    }
  }

  // store bf16 in MFMA B-frag order: element j of lane (quad*16+c16) of frag (kh,nt)
  const int kh = i >> 5, quad = (i >> 3) & 3, j8 = i & 7;
  #pragma unroll
  for (int rr = 0; rr < 4; ++rr) {
    const int b = b0 + rr;
    #pragma unroll
    for (int jj = 0; jj < 4; ++jj) {
      const int j = j0 + jj;
      const float v = acc[rr][jj] + hb2[g * 4096 + i * 64 + j];
      const int col = g * 64 + j;
      const int nt = col >> 4, c16 = col & 15;
      const int lane = quad * 16 + c16;
      whb[(size_t)((b * 32 + kh * 16 + nt) * 64 + lane) * 8 + j8] = f2bf(v);
    }
  }
}

// ---------------------------------------------------------------------------
// Kernel 3 (unchanged from R3): grid (11 x-tiles of 32 rows, 64 batches).
// 704 blocks @ 3 blocks/CU -> single co-residency pass; 2 independent
// row-tiles per wave per step (2x ILP across the MFMA->nonlin chain).
// ---------------------------------------------------------------------------
__global__ __launch_bounds__(256, 3) void k_lstm(
    const float* __restrict__ xg, const float* __restrict__ wx_ws,
    const float* __restrict__ bg_ws, const unsigned short* __restrict__ whb,
    const float* __restrict__ fc1W, const float* __restrict__ fc1b,
    const float* __restrict__ fc2W, const float* __restrict__ fc2b,
    float* __restrict__ out)
{
  const int rb = blockIdx.x, b = blockIdx.y, tid = threadIdx.x;
  const int wave = tid >> 6, lane = tid & 63, quad = lane >> 4, c16 = lane & 15;
  const int n0 = rb * 32;

  __shared__ __align__(16) unsigned short Hs[2][2][16][72];  // [buf][tile][row][col]
  __shared__ float Xs[TT][32];
  __shared__ float fc1s[HH * 32];
  __shared__ float fc2s[32 * OO];
  __shared__ float HIDs[32][36];
  __shared__ float fc1bs[32];
  __shared__ float fc2bs[OO];

  for (int idx = tid; idx < TT * 32; idx += 256) {
    const int t = idx >> 5, r = idx & 31, n = n0 + r;
    Xs[t][r] = (n < NN) ? xg[b * (TT * NN) + t * NN + n] : 0.f;
  }
  for (int idx = tid; idx < HH * 32; idx += 256) fc1s[idx] = fc1W[idx];
  for (int idx = tid; idx < 32 * OO; idx += 256) fc2s[idx] = fc2W[idx];
  if (tid < 32) fc1bs[tid] = fc1b[tid];
  if (tid < OO) fc2bs[tid] = fc2b[tid];

  float wxv[4], bgv[4];
  #pragma unroll
  for (int g = 0; g < 4; ++g) {
    wxv[g] = wx_ws[b * 256 + g * 64 + wave * 16 + c16];
    bgv[g] = bg_ws[b * 256 + g * 64 + wave * 16 + c16];
  }
  bf8 wf[2][4];
  #pragma unroll
  for (int kh = 0; kh < 2; ++kh)
    #pragma unroll
    for (int g = 0; g < 4; ++g)
      wf[kh][g] = *(const bf8*)(whb + (size_t)((b * 32 + kh * 16 + g * 4 + wave) * 64 + lane) * 8);

  float cst[2][4];
  #pragma unroll
  for (int ta = 0; ta < 2; ++ta)
    #pragma unroll
    for (int r = 0; r < 4; ++r) cst[ta][r] = 0.f;

  __syncthreads();

  #pragma unroll 1
  for (int t = 0; t < TT; ++t) {
    bf8 af[2][2];
    if (t > 0) {
      #pragma unroll
      for (int ta = 0; ta < 2; ++ta) {
        af[ta][0] = *(const bf8*)&Hs[(t - 1) & 1][ta][c16][quad * 8];
        af[ta][1] = *(const bf8*)&Hs[(t - 1) & 1][ta][c16][32 + quad * 8];
      }
    }
    f4 ac[2][4];
    #pragma unroll
    for (int ta = 0; ta < 2; ++ta) {
      float xr[4];
      #pragma unroll
      for (int r = 0; r < 4; ++r) xr[r] = Xs[t][ta * 16 + quad * 4 + r];
      #pragma unroll
      for (int g = 0; g < 4; ++g)
        #pragma unroll
        for (int r = 0; r < 4; ++r)
          ac[ta][g][r] = fmaf(xr[r], wxv[g], bgv[g]);
    }
    if (t > 0) {
      #pragma unroll
      for (int ta = 0; ta < 2; ++ta)
        #pragma unroll
        for (int g = 0; g < 4; ++g) {
          ac[ta][g] = __builtin_amdgcn_mfma_f32_16x16x32_bf16(af[ta][0], wf[0][g], ac[ta][g], 0, 0, 0);
          ac[ta][g] = __builtin_amdgcn_mfma_f32_16x16x32_bf16(af[ta][1], wf[1][g], ac[ta][g], 0, 0, 0);
        }
    }
    #pragma unroll
    for (int ta = 0; ta < 2; ++ta)
      #pragma unroll
      for (int r = 0; r < 4; ++r) {
        const float gg = tanhfast(ac[ta][0][r]);
        const float ii = sigf(ac[ta][1][r]);
        const float ff = sigf(ac[ta][2][r]);
        const float oo = sigf(ac[ta][3][r]);
        const float cc = fmaf(gg, ii, cst[ta][r] * ff);
        cst[ta][r] = cc;
        const float hh = tanhfast(cc) * oo;
        Hs[t & 1][ta][quad * 4 + r][wave * 16 + c16] = f2bf(hh);
      }
    __syncthreads();
  }

  // ---- head, fp32. final h is in Hs[1]. ----
  {
    const int row32 = tid & 31, uu = tid >> 5;
    const int ta = row32 >> 4, row = row32 & 15;
    float hacc[4];
    #pragma unroll
    for (int j = 0; j < 4; ++j) hacc[j] = fc1bs[uu * 4 + j];
    #pragma unroll
    for (int kc = 0; kc < 8; ++kc) {
      const bf8 hv = *(const bf8*)&Hs[1][ta][row][kc * 8];
      #pragma unroll
      for (int j8 = 0; j8 < 8; ++j8) {
        const float hk = fmaxf(bf2f((unsigned short)hv[j8]), 0.f);  // relu(h)
        const int k = kc * 8 + j8;
        #pragma unroll
        for (int j = 0; j < 4; ++j)
          hacc[j] = fmaf(hk, fc1s[k * 32 + uu * 4 + j], hacc[j]);
      }
    }
    #pragma unroll
    for (int j = 0; j < 4; ++j)
      HIDs[row32][uu * 4 + j] = fmaxf(hacc[j], 0.f);
  }
  __syncthreads();
  for (int idx = tid; idx < 32 * OO; idx += 256) {
    const int o = idx >> 5, row32 = idx & 31;
    float a = fc2bs[o];
    #pragma unroll
    for (int k = 0; k < 32; ++k)
      a = fmaf(HIDs[row32][k], fc2s[k * OO + o], a);
    const int n = n0 + row32;
    if (n < NN)
      out[b * (OO * NN) + o * NN + n] = a;
  }
}

// ---------------------------------------------------------------------------
extern "C" void kernel_launch(void* const* d_in, const int* in_sizes, int n_in,
                              void* d_out, int out_size, void* d_ws, size_t ws_size,
                              hipStream_t stream) {
  const float* x    = (const float*)d_in[0];
  const float* xw1  = (const float*)d_in[1];
  const float* xb1  = (const float*)d_in[2];
  const float* xw2  = (const float*)d_in[3];
  const float* xb2  = (const float*)d_in[4];
  const float* hw1  = (const float*)d_in[5];
  const float* hb1  = (const float*)d_in[6];
  const float* hw2  = (const float*)d_in[7];
  const float* hb2  = (const float*)d_in[8];
  const float* bw1  = (const float*)d_in[9];
  const float* bb1  = (const float*)d_in[10];
  const float* bw2  = (const float*)d_in[11];
  const float* bb2  = (const float*)d_in[12];
  const float* fc1W = (const float*)d_in[13];
  const float* fc1b = (const float*)d_in[14];
  const float* fc2W = (const float*)d_in[15];
  const float* fc2b = (const float*)d_in[16];
  float* out = (float*)d_out;

  float* ws = (float*)d_ws;
  float* hid_ws = ws;                        // [4][64][128]      = 32768 floats
  float* wx_ws  = ws + 32768;                // [64][256]         = 16384
  float* bg_ws  = ws + 49152;                // [64][256]         = 16384
  float* xg_ws  = ws + 65536;                // [64][12][325]     = 249600
  unsigned short* whb = (unsigned short*)(ws + 65536 + BB * TT * NN);  // 1048576 u16

  k_meta<<<64, 256, 0, stream>>>(x, xw1, xb1, xw2, xb2, hw1, hb1, bw1, bb1,
                                 bw2, bb2, hid_ws, wx_ws, bg_ws);
  k_wh<<<256, 256, 0, stream>>>(x, hw2, hb2, hid_ws, whb, xg_ws);
  k_lstm<<<dim3(11, 64), 256, 0, stream>>>(xg_ws, wx_ws, bg_ws, whb,
                                           fc1W, fc1b, fc2W, fc2b, out);
}

// Round 5
// 214.507 us; speedup vs baseline: 1.1514x; 1.0465x over previous
//
#include <hip/hip_runtime.h>
#include <stdint.h>

#define TT 12
#define NN 325
#define HH 64
#define EE 32
#define LHH 128
#define OO 12
#define CIN 97
#define MOFF 65
#define BB 64

typedef __attribute__((ext_vector_type(8))) short bf8;
typedef __attribute__((ext_vector_type(4))) float f4;

__device__ __forceinline__ float sigf(float x) {
  return __builtin_amdgcn_rcpf(1.f + __builtin_amdgcn_exp2f(-1.4426950408889634f * x));
}
__device__ __forceinline__ float tanhfast(float x) {
  // tanh(x) = 1 - 2/(1+e^{2x});  e^{2x} = 2^{2x*log2e}
  return 1.f - 2.f * __builtin_amdgcn_rcpf(1.f + __builtin_amdgcn_exp2f(2.8853900817779268f * x));
}
__device__ __forceinline__ unsigned short f2bf(float f) {  // RNE float->bf16
  unsigned int u = __float_as_uint(f);
  u += 0x7fffu + ((u >> 16) & 1u);
  return (unsigned short)(u >> 16);
}
__device__ __forceinline__ float bf2f(unsigned short s) {
  return __uint_as_float(((unsigned int)s) << 16);
}

// ---------------------------------------------------------------------------
// Kernel 1 v2: grid 256 = (4 gates x 64 batches) -- was grid 64 (0.25 blk/CU).
// Block (g,b): meta mean, 3 MLP gate-g hiddens, lwx/lb outputs via 4-way
// K-partials. 4x more blocks, ~4x less work per thread.
// ---------------------------------------------------------------------------
__global__ __launch_bounds__(256) void k_meta(
    const float* __restrict__ x,
    const float* __restrict__ xw1, const float* __restrict__ xb1,
    const float* __restrict__ xw2, const float* __restrict__ xb2,
    const float* __restrict__ hw1, const float* __restrict__ hb1,
    const float* __restrict__ bw1, const float* __restrict__ bb1,
    const float* __restrict__ bw2, const float* __restrict__ bb2,
    float* __restrict__ hid_ws, float* __restrict__ wx_ws,
    float* __restrict__ bg_ws)
{
  const int g = blockIdx.x >> 6, b = blockIdx.x & 63, tid = threadIdx.x;
  __shared__ float mpart[TT][EE];
  __shared__ float meta_s[EE];
  __shared__ float hid3[3][LHH];    // gate-g hiddens: [0]=lwx, [1]=lwh, [2]=lb
  __shared__ float psum[2][4][HH];  // [isb][K-part][h]

  for (int idx = tid; idx < TT * EE; idx += 256) {
    const int t = idx >> 5, e = idx & 31;
    mpart[t][e] = x[(size_t)((b * TT + t) * NN) * CIN + MOFF + e];
  }
  __syncthreads();
  if (tid < EE) {
    float s = 0.f;
    #pragma unroll
    for (int t = 0; t < TT; ++t) s += mpart[t][tid];
    meta_s[tid] = s * (1.f / 12.f);
  }
  __syncthreads();

  // 3 MLP hiddens for gate g (384 dots of 32)
  for (int idx = tid; idx < 3 * LHH; idx += 256) {
    const int mlp = idx >> 7, l = idx & 127;
    const float* W1 = (mlp == 0) ? xw1 : ((mlp == 1) ? hw1 : bw1);
    const float* B1 = (mlp == 0) ? xb1 : ((mlp == 1) ? hb1 : bb1);
    float a = B1[g * LHH + l];
    const float* w = W1 + (size_t)g * (EE * LHH) + l;
    #pragma unroll
    for (int e = 0; e < EE; ++e) a = fmaf(meta_s[e], w[e * LHH], a);
    a = fmaxf(a, 0.f);
    hid3[mlp][l] = a;
    if (mlp == 1) hid_ws[g * (BB * LHH) + b * LHH + l] = a;  // for k_wh
  }
  __syncthreads();

  // lwx / lb outputs: 64 cols each, 4-way K-split partials
  {
    const int part = tid >> 6, h = tid & 63;
    float ax = 0.f, ab = 0.f;
    const float* wxp = xw2 + (size_t)g * (LHH * HH) + h;
    const float* wbp = bw2 + (size_t)g * (LHH * HH) + h;
    #pragma unroll
    for (int ll = 0; ll < 32; ++ll) {
      const int l = part * 32 + ll;
      ax = fmaf(hid3[0][l], wxp[l * HH], ax);
      ab = fmaf(hid3[2][l], wbp[l * HH], ab);
    }
    psum[0][part][h] = ax;
    psum[1][part][h] = ab;
  }
  __syncthreads();
  if (tid < 128) {
    const int isb = tid >> 6, h = tid & 63;
    const float bias = (isb ? bb2 : xb2)[g * HH + h];
    const float a = bias + psum[isb][0][h] + psum[isb][1][h]
                         + psum[isb][2][h] + psum[isb][3][h];
    (isb ? bg_ws : wx_ws)[b * 256 + g * 64 + h] = a;
  }
}

// ---------------------------------------------------------------------------
// Kernel 2 v2: grid 1024 = (4 g x 64 col-slices x 4 batch-quarters) -- was
// 256 (1 blk/CU). Block: hid(16b x 128) @ W2-slice(128 x 64) -> bf16 Wh in
// MFMA B-frag order (formula identical to R1-R4). 2x2 register tile/thread.
// x-signal gather spread across all 1024 blocks (1 elem/thread).
// ---------------------------------------------------------------------------
__global__ __launch_bounds__(256) void k_wh(
    const float* __restrict__ x,
    const float* __restrict__ hw2, const float* __restrict__ hb2,
    const float* __restrict__ hid_ws, unsigned short* __restrict__ whb,
    float* __restrict__ xg)
{
  const int g = blockIdx.x >> 8, i = (blockIdx.x >> 2) & 63, bq = blockIdx.x & 3;
  const int tid = threadIdx.x;
  __shared__ float hs[16][132];       // hid[b][l], padded (rows 528B, 16B-mult)
  __shared__ float w2s[LHH][HH];      // W2 slice [l][j] for cols i*64..i*64+63

  // x-signal gather: 249600 elems / 1024 blocks = 244 (1 per thread)
  {
    const int flat = blockIdx.x * 244 + tid;
    if (tid < 244 && flat < BB * TT * NN) {
      const int b = flat / (TT * NN);
      const int r = flat - b * (TT * NN);
      const int t = r / NN;
      const int n = r - t * NN;
      xg[flat] = x[(size_t)((b * TT + t) * NN + n) * CIN];
    }
  }

  for (int idx = tid; idx < 16 * LHH; idx += 256)
    hs[idx >> 7][idx & 127] =
        hid_ws[g * (BB * LHH) + (bq * 16 + (idx >> 7)) * LHH + (idx & 127)];
  for (int idx = tid; idx < LHH * HH; idx += 256)
    w2s[idx >> 6][idx & 63] =
        hw2[(size_t)(g * LHH + (idx >> 6)) * 4096 + i * 64 + (idx & 63)];
  __syncthreads();

  // 2 rows x 2 cols per thread over K=128
  const int r0 = (tid >> 5) * 2, j0 = (tid & 31) * 2;
  float acc[2][2] = {};
  for (int l = 0; l < LHH; l += 4) {
    const f4 h0 = *(const f4*)&hs[r0][l];
    const f4 h1 = *(const f4*)&hs[r0 + 1][l];
    #pragma unroll
    for (int ll = 0; ll < 4; ++ll) {
      const float w0 = w2s[l + ll][j0];
      const float w1 = w2s[l + ll][j0 + 1];
      acc[0][0] = fmaf(h0[ll], w0, acc[0][0]);
      acc[0][1] = fmaf(h0[ll], w1, acc[0][1]);
      acc[1][0] = fmaf(h1[ll], w0, acc[1][0]);
      acc[1][1] = fmaf(h1[ll], w1, acc[1][1]);
    }
  }

  // store bf16 in MFMA B-frag order (same formula as before)
  const int kh = i >> 5, quad = (i >> 3) & 3, j8 = i & 7;
  #pragma unroll
  for (int rr = 0; rr < 2; ++rr) {
    const int b = bq * 16 + r0 + rr;
    #pragma unroll
    for (int jj = 0; jj < 2; ++jj) {
      const int j = j0 + jj;
      const float v = acc[rr][jj] + hb2[g * 4096 + i * 64 + j];
      const int col = g * 64 + j;
      const int nt = col >> 4, c16 = col & 15;
      const int lane = quad * 16 + c16;
      whb[(size_t)((b * 32 + kh * 16 + nt) * 64 + lane) * 8 + j8] = f2bf(v);
    }
  }
}

// ---------------------------------------------------------------------------
// Kernel 3 (byte-identical to R4): grid (11 x-tiles of 32 rows, 64 batches).
// ---------------------------------------------------------------------------
__global__ __launch_bounds__(256, 3) void k_lstm(
    const float* __restrict__ xg, const float* __restrict__ wx_ws,
    const float* __restrict__ bg_ws, const unsigned short* __restrict__ whb,
    const float* __restrict__ fc1W, const float* __restrict__ fc1b,
    const float* __restrict__ fc2W, const float* __restrict__ fc2b,
    float* __restrict__ out)
{
  const int rb = blockIdx.x, b = blockIdx.y, tid = threadIdx.x;
  const int wave = tid >> 6, lane = tid & 63, quad = lane >> 4, c16 = lane & 15;
  const int n0 = rb * 32;

  __shared__ __align__(16) unsigned short Hs[2][2][16][72];  // [buf][tile][row][col]
  __shared__ float Xs[TT][32];
  __shared__ float fc1s[HH * 32];
  __shared__ float fc2s[32 * OO];
  __shared__ float HIDs[32][36];
  __shared__ float fc1bs[32];
  __shared__ float fc2bs[OO];

  for (int idx = tid; idx < TT * 32; idx += 256) {
    const int t = idx >> 5, r = idx & 31, n = n0 + r;
    Xs[t][r] = (n < NN) ? xg[b * (TT * NN) + t * NN + n] : 0.f;
  }
  for (int idx = tid; idx < HH * 32; idx += 256) fc1s[idx] = fc1W[idx];
  for (int idx = tid; idx < 32 * OO; idx += 256) fc2s[idx] = fc2W[idx];
  if (tid < 32) fc1bs[tid] = fc1b[tid];
  if (tid < OO) fc2bs[tid] = fc2b[tid];

  float wxv[4], bgv[4];
  #pragma unroll
  for (int g = 0; g < 4; ++g) {
    wxv[g] = wx_ws[b * 256 + g * 64 + wave * 16 + c16];
    bgv[g] = bg_ws[b * 256 + g * 64 + wave * 16 + c16];
  }
  bf8 wf[2][4];
  #pragma unroll
  for (int kh = 0; kh < 2; ++kh)
    #pragma unroll
    for (int g = 0; g < 4; ++g)
      wf[kh][g] = *(const bf8*)(whb + (size_t)((b * 32 + kh * 16 + g * 4 + wave) * 64 + lane) * 8);

  float cst[2][4];
  #pragma unroll
  for (int ta = 0; ta < 2; ++ta)
    #pragma unroll
    for (int r = 0; r < 4; ++r) cst[ta][r] = 0.f;

  __syncthreads();

  #pragma unroll 1
  for (int t = 0; t < TT; ++t) {
    bf8 af[2][2];
    if (t > 0) {
      #pragma unroll
      for (int ta = 0; ta < 2; ++ta) {
        af[ta][0] = *(const bf8*)&Hs[(t - 1) & 1][ta][c16][quad * 8];
        af[ta][1] = *(const bf8*)&Hs[(t - 1) & 1][ta][c16][32 + quad * 8];
      }
    }
    f4 ac[2][4];
    #pragma unroll
    for (int ta = 0; ta < 2; ++ta) {
      float xr[4];
      #pragma unroll
      for (int r = 0; r < 4; ++r) xr[r] = Xs[t][ta * 16 + quad * 4 + r];
      #pragma unroll
      for (int g = 0; g < 4; ++g)
        #pragma unroll
        for (int r = 0; r < 4; ++r)
          ac[ta][g][r] = fmaf(xr[r], wxv[g], bgv[g]);
    }
    if (t > 0) {
      #pragma unroll
      for (int ta = 0; ta < 2; ++ta)
        #pragma unroll
        for (int g = 0; g < 4; ++g) {
          ac[ta][g] = __builtin_amdgcn_mfma_f32_16x16x32_bf16(af[ta][0], wf[0][g], ac[ta][g], 0, 0, 0);
          ac[ta][g] = __builtin_amdgcn_mfma_f32_16x16x32_bf16(af[ta][1], wf[1][g], ac[ta][g], 0, 0, 0);
        }
    }
    #pragma unroll
    for (int ta = 0; ta < 2; ++ta)
      #pragma unroll
      for (int r = 0; r < 4; ++r) {
        const float gg = tanhfast(ac[ta][0][r]);
        const float ii = sigf(ac[ta][1][r]);
        const float ff = sigf(ac[ta][2][r]);
        const float oo = sigf(ac[ta][3][r]);
        const float cc = fmaf(gg, ii, cst[ta][r] * ff);
        cst[ta][r] = cc;
        const float hh = tanhfast(cc) * oo;
        Hs[t & 1][ta][quad * 4 + r][wave * 16 + c16] = f2bf(hh);
      }
    __syncthreads();
  }

  // ---- head, fp32. final h is in Hs[1]. ----
  {
    const int row32 = tid & 31, uu = tid >> 5;
    const int ta = row32 >> 4, row = row32 & 15;
    float hacc[4];
    #pragma unroll
    for (int j = 0; j < 4; ++j) hacc[j] = fc1bs[uu * 4 + j];
    #pragma unroll
    for (int kc = 0; kc < 8; ++kc) {
      const bf8 hv = *(const bf8*)&Hs[1][ta][row][kc * 8];
      #pragma unroll
      for (int j8 = 0; j8 < 8; ++j8) {
        const float hk = fmaxf(bf2f((unsigned short)hv[j8]), 0.f);  // relu(h)
        const int k = kc * 8 + j8;
        #pragma unroll
        for (int j = 0; j < 4; ++j)
          hacc[j] = fmaf(hk, fc1s[k * 32 + uu * 4 + j], hacc[j]);
      }
    }
    #pragma unroll
    for (int j = 0; j < 4; ++j)
      HIDs[row32][uu * 4 + j] = fmaxf(hacc[j], 0.f);
  }
  __syncthreads();
  for (int idx = tid; idx < 32 * OO; idx += 256) {
    const int o = idx >> 5, row32 = idx & 31;
    float a = fc2bs[o];
    #pragma unroll
    for (int k = 0; k < 32; ++k)
      a = fmaf(HIDs[row32][k], fc2s[k * OO + o], a);
    const int n = n0 + row32;
    if (n < NN)
      out[b * (OO * NN) + o * NN + n] = a;
  }
}

// ---------------------------------------------------------------------------
extern "C" void kernel_launch(void* const* d_in, const int* in_sizes, int n_in,
                              void* d_out, int out_size, void* d_ws, size_t ws_size,
                              hipStream_t stream) {
  const float* x    = (const float*)d_in[0];
  const float* xw1  = (const float*)d_in[1];
  const float* xb1  = (const float*)d_in[2];
  const float* xw2  = (const float*)d_in[3];
  const float* xb2  = (const float*)d_in[4];
  const float* hw1  = (const float*)d_in[5];
  const float* hb1  = (const float*)d_in[6];
  const float* hw2  = (const float*)d_in[7];
  const float* hb2  = (const float*)d_in[8];
  const float* bw1  = (const float*)d_in[9];
  const float* bb1  = (const float*)d_in[10];
  const float* bw2  = (const float*)d_in[11];
  const float* bb2  = (const float*)d_in[12];
  const float* fc1W = (const float*)d_in[13];
  const float* fc1b = (const float*)d_in[14];
  const float* fc2W = (const float*)d_in[15];
  const float* fc2b = (const float*)d_in[16];
  float* out = (float*)d_out;

  float* ws = (float*)d_ws;
  float* hid_ws = ws;                        // [4][64][128]      = 32768 floats
  float* wx_ws  = ws + 32768;                // [64][256]         = 16384
  float* bg_ws  = ws + 49152;                // [64][256]         = 16384
  float* xg_ws  = ws + 65536;                // [64][12][325]     = 249600
  unsigned short* whb = (unsigned short*)(ws + 65536 + BB * TT * NN);  // 1048576 u16

  k_meta<<<256, 256, 0, stream>>>(x, xw1, xb1, xw2, xb2, hw1, hb1, bw1, bb1,
                                  bw2, bb2, hid_ws, wx_ws, bg_ws);
  k_wh<<<1024, 256, 0, stream>>>(x, hw2, hb2, hid_ws, whb, xg_ws);
  k_lstm<<<dim3(11, 64), 256, 0, stream>>>(xg_ws, wx_ws, bg_ws, whb,
                                           fc1W, fc1b, fc2W, fc2b, out);
}